// Round 3
// baseline (438.174 us; speedup 1.0000x reference)
//
#include <hip/hip_runtime.h>
#include <cfloat>
#include <climits>
#include <math.h>

#define BN 16
#define QN 4096
#define GN 256
#define CN 80

typedef unsigned long long u64;

__device__ __forceinline__ bool lexLessF(float a, int ia, float b, int ib) {
    return (a < b) || (a == b && ia < ib);
}

// ---------------- zero init (rowmask + colcnt + staleCount) ----------------
__global__ void k_zero(u64* __restrict__ p, int n) {
    int i = blockIdx.x * blockDim.x + threadIdx.x;
    if (i < n) p[i] = 0ull;
}

// ---------------- fg per query row (f32, exact reference order) ----------------
__global__ __launch_bounds__(256) void k_fg(const float* __restrict__ gtb,
                                            const float* __restrict__ pb,
                                            unsigned char* __restrict__ fg) {
#pragma clang fp contract(off)
    int b = blockIdx.y;
    int i = blockIdx.x * 256 + threadIdx.x;
    __shared__ float s[GN][8];
    for (int j = threadIdx.x; j < GN; j += 256) {
        const float* g = gtb + ((size_t)(b * GN + j)) * 4;
        float g0 = g[0], g1 = g[1], g2 = g[2], g3 = g[3];
        float gcx = (g0 + g2) * 0.5f, gcy = (g1 + g3) * 0.5f;
        float gw = g2 - g0, gh = g3 - g1;
        float x0 = gcx - gw * 0.5f, y0 = gcy - gh * 0.5f;
        float x1 = gcx + gw * 0.5f, y1 = gcy + gh * 0.5f;
        float w = x1 - x0, h = y1 - y0;
        s[j][0] = x0; s[j][1] = y0; s[j][2] = x1; s[j][3] = y1;
        s[j][4] = gcx - 2.5f * w; s[j][5] = gcx + 2.5f * w;
        s[j][6] = gcy - 2.5f * h; s[j][7] = gcy + 2.5f * h;
    }
    __syncthreads();
    const float4 bb = *reinterpret_cast<const float4*>(pb + ((size_t)(b * QN + i)) * 4);
    float ax = (bb.x + bb.z) * 0.5f, ay = (bb.y + bb.w) * 0.5f;
    bool anyib = false, anyic = false;
    for (int j = 0; j < GN; j++) {
        bool ib = (ax > s[j][0]) && (ax < s[j][2]) && (ay > s[j][1]) && (ay < s[j][3]);
        bool ic = (ax > s[j][4]) && (ax < s[j][5]) && (ay > s[j][6]) && (ay < s[j][7]);
        anyib |= ib; anyic |= ic;
    }
    fg[(size_t)b * QN + i] = (anyib || anyic) ? 1 : 0;
}

// ---------------- cost matrix (f32) + per-column dk selection ----------------
__global__ __launch_bounds__(256) void k_cost(
    const float* __restrict__ logits, const float* __restrict__ pboxes,
    const float* __restrict__ pposes, const int* __restrict__ labels,
    const float* __restrict__ gtb, const float* __restrict__ gtt,
    const float* __restrict__ gtr, const float* __restrict__ img,
    const float* __restrict__ imgt, const unsigned char* __restrict__ fg,
    float* __restrict__ cost, u64* __restrict__ rowmask) {
#pragma clang fp contract(off)
    const int t = threadIdx.x;
    const int b = blockIdx.x >> 8, j = blockIdx.x & 255;
    const int lab = labels[b * GN + j];
    const float* g = gtb + ((size_t)(b * GN + j)) * 4;
    const float g0 = g[0], g1 = g[1], g2 = g[2], g3 = g[3];
    const float* it = imgt + ((size_t)(b * GN + j)) * 4;
    const float gn0 = g0 / it[0], gn1 = g1 / it[1], gn2 = g2 / it[2], gn3 = g3 / it[3];
    const float im0 = img[b * 4 + 0], im1 = img[b * 4 + 1], im2 = img[b * 4 + 2], im3 = img[b * 4 + 3];
    const float ga = (g2 - g0) * (g3 - g1);
    const float gcx = (g0 + g2) * 0.5f, gcy = (g1 + g3) * 0.5f;
    const float gw = g2 - g0, gh = g3 - g1;
    const float X0 = gcx - gw * 0.5f, Y0 = gcy - gh * 0.5f;
    const float X1 = gcx + gw * 0.5f, Y1 = gcy + gh * 0.5f;
    const float W = X1 - X0, H = Y1 - Y0;
    const float LOX = gcx - 2.5f * W, HIX = gcx + 2.5f * W;
    const float LOY = gcy - 2.5f * H, HIY = gcy + 2.5f * H;
    const float t0 = gtt[(b * GN + j) * 3 + 0], t1 = gtt[(b * GN + j) * 3 + 1], t2 = gtt[(b * GN + j) * 3 + 2];
    const float r0 = gtr[(b * GN + j) * 3 + 0], r1 = gtr[(b * GN + j) * 3 + 1], r2 = gtr[(b * GN + j) * 3 + 2];

    float cv[5]; int ci[5]; float iv[5];
#pragma unroll
    for (int k = 0; k < 5; k++) { cv[k] = FLT_MAX; ci[k] = INT_MAX; iv[k] = -1.0f; }

    float* crow = cost + ((size_t)(b * GN + j)) * QN;

    for (int kk = 0; kk < QN / 256; kk++) {
        int i = t + kk * 256;
        const float4 bx = *reinterpret_cast<const float4*>(pboxes + ((size_t)(b * QN + i)) * 4);
        const float b0 = bx.x, b1 = bx.y, b2 = bx.z, b3 = bx.w;
        const float* ps = pposes + ((size_t)(b * QN + i)) * 6;
        const float p0 = ps[0], p1 = ps[1], p2 = ps[2], p3 = ps[3], p4 = ps[4], p5 = ps[5];
        const float x = logits[((size_t)(b * QN + i)) * CN + lab];
        const unsigned char fgv = fg[(size_t)b * QN + i];

        // focal class cost: f32 step sequence, transcendentals correctly rounded via f64
        float e = (float)exp(-(double)x);
        float pr = 1.0f / (1.0f + e);
        float om = 1.0f - pr;
        float lneg = (float)log((double)(om + 1e-8f));
        float lpos = (float)log((double)(pr + 1e-8f));
        float neg = (0.75f * (pr * pr)) * (-lneg);
        float pos = (0.25f * (om * om)) * (-lpos);
        float cc = pos - neg;

        // iou / giou (f32, reference op order)
        float a1 = (b2 - b0) * (b3 - b1);
        float ltx = fmaxf(b0, g0), lty = fmaxf(b1, g1);
        float rbx = fminf(b2, g2), rby = fminf(b3, g3);
        float w = fmaxf(rbx - ltx, 0.0f), h = fmaxf(rby - lty, 0.0f);
        float inter = w * h;
        float uni = (a1 + ga) - inter;
        float iou = inter / uni;
        float eltx = fminf(b0, g0), elty = fminf(b1, g1);
        float erbx = fmaxf(b2, g2), erby = fmaxf(b3, g3);
        float ew = fmaxf(erbx - eltx, 0.0f), eh = fmaxf(erby - elty, 0.0f);
        float earea = ew * eh;
        float giou = iou - (earea - uni) / earea;

        // normalized bbox L1 (sequential f32)
        float cb = fabsf(b0 / im0 - gn0);
        cb = cb + fabsf(b1 / im1 - gn1);
        cb = cb + fabsf(b2 / im2 - gn2);
        cb = cb + fabsf(b3 / im3 - gn3);
        // pose L1
        float ct = fabsf(p0 - t0); ct = ct + fabsf(p1 - t1); ct = ct + fabsf(p2 - t2);
        float cr = fabsf(p3 - r0); cr = cr + fabsf(p4 - r1); cr = cr + fabsf(p5 - r2);
        // both = in_box & in_ctr
        float ax = (b0 + b2) * 0.5f, ay = (b1 + b3) * 0.5f;
        bool ib = (ax > X0) && (ax < X1) && (ay > Y0) && (ay < Y1);
        bool ic = (ax > LOX) && (ax < HIX) && (ay > LOY) && (ay < HIY);
        bool nb = !(ib && ic);

        // combine fully in f32, reference left-to-right order
        float d = 5.0f * cb;
        d = d + 2.0f * cc;
        d = d + 2.0f * (-giou);
        d = d + (nb ? 100.0f : 0.0f);
        d = d + ct;
        d = d + cr;
        d = d + (fgv ? 0.0f : 10000.0f);

        crow[i] = d;

        // per-thread bottom-5 (cost,i) lex, ascending
        if (lexLessF(d, i, cv[4], ci[4])) {
            int k = 4;
            while (k > 0 && lexLessF(d, i, cv[k - 1], ci[k - 1])) {
                cv[k] = cv[k - 1]; ci[k] = ci[k - 1]; k--;
            }
            cv[k] = d; ci[k] = i;
        }
        // per-thread top-5 iou, descending
        if (iou > iv[4]) {
            int k = 4;
            while (k > 0 && iou > iv[k - 1]) { iv[k] = iv[k - 1]; k--; }
            iv[k] = iou;
        }
    }

    __shared__ float scv[256 * 5];
    __shared__ int sci[256 * 5];
    __shared__ float siv[256 * 5];
#pragma unroll
    for (int k = 0; k < 5; k++) { scv[t * 5 + k] = cv[k]; sci[t * 5 + k] = ci[k]; siv[t * 5 + k] = iv[k]; }

    for (int s = 128; s > 0; s >>= 1) {
        __syncthreads();
        if (t < s) {
            float av[5], bv[5], rv[5];
            int ai[5], bi[5], ri[5];
#pragma unroll
            for (int k = 0; k < 5; k++) {
                av[k] = scv[t * 5 + k]; ai[k] = sci[t * 5 + k];
                bv[k] = scv[(t + s) * 5 + k]; bi[k] = sci[(t + s) * 5 + k];
            }
            int pa = 0, pb = 0;
#pragma unroll
            for (int k = 0; k < 5; k++) {
                bool takeA = lexLessF(av[pa], ai[pa], bv[pb], bi[pb]);
                if (takeA) { rv[k] = av[pa]; ri[k] = ai[pa]; pa++; }
                else { rv[k] = bv[pb]; ri[k] = bi[pb]; pb++; }
            }
#pragma unroll
            for (int k = 0; k < 5; k++) { scv[t * 5 + k] = rv[k]; sci[t * 5 + k] = ri[k]; }
            float fa[5], fb[5], fr[5];
#pragma unroll
            for (int k = 0; k < 5; k++) { fa[k] = siv[t * 5 + k]; fb[k] = siv[(t + s) * 5 + k]; }
            pa = 0; pb = 0;
#pragma unroll
            for (int k = 0; k < 5; k++) {
                if (fa[pa] >= fb[pb]) { fr[k] = fa[pa]; pa++; }
                else { fr[k] = fb[pb]; pb++; }
            }
#pragma unroll
            for (int k = 0; k < 5; k++) siv[t * 5 + k] = fr[k];
        }
    }

    if (t == 0) {
#pragma clang fp contract(off)
        float sum = ((((siv[0] + siv[1]) + siv[2]) + siv[3]) + siv[4]);  // sequential, desc order
        int dk = (int)sum;          // trunc toward zero (sum >= 0)
        if (dk < 1) dk = 1;
        if (dk > 5) dk = 5;
        for (int k = 0; k < dk; k++) {
            int i = sci[k];
            atomicOr(&rowmask[((size_t)(b * QN + i)) * 4 + (j >> 6)], 1ull << (j & 63));
        }
    }
}

// ---------------- stale detect + pen + colcnt (non-stale rows) ----------------
__global__ __launch_bounds__(256) void k_stalepen(u64* __restrict__ rowmask,
                                                  unsigned char* __restrict__ pen,
                                                  int* __restrict__ colcnt,
                                                  int* __restrict__ staleCount,
                                                  int* __restrict__ staleList) {
    int b = blockIdx.y;
    int i = blockIdx.x * 256 + threadIdx.x;
    u64* rm = rowmask + ((size_t)(b * QN + i)) * 4;
    u64 w0 = rm[0], w1 = rm[1], w2 = rm[2], w3 = rm[3];
    int cnt = __popcll(w0) + __popcll(w1) + __popcll(w2) + __popcll(w3);
    pen[(size_t)b * QN + i] = (cnt > 0) ? 1 : 0;
    if (cnt > 1) {
        int idx = atomicAdd(staleCount, 1);
        staleList[idx] = (b << 12) | i;
    } else if (cnt == 1) {
        u64 w; int base;
        if (w0) { w = w0; base = 0; }
        else if (w1) { w = w1; base = 64; }
        else if (w2) { w = w2; base = 128; }
        else { w = w3; base = 192; }
        int j = base + (__ffsll((long long)w) - 1);
        atomicAdd(&colcnt[b * GN + j], 1);
    }
}

// ---------------- stale fix: row -> one_hot(argmin_j cost) (unpenalized, exact f32) ----------------
__global__ __launch_bounds__(256) void k_stalefix(const float* __restrict__ cost,
                                                  u64* __restrict__ rowmask,
                                                  int* __restrict__ colcnt,
                                                  const int* __restrict__ staleCount,
                                                  const int* __restrict__ staleList) {
    int gtid = blockIdx.x * blockDim.x + threadIdx.x;
    int wid = gtid >> 6;
    int lane = threadIdx.x & 63;
    int nw = (gridDim.x * blockDim.x) >> 6;
    int n = *staleCount;
    for (int e = wid; e < n; e += nw) {
        int pk = staleList[e];
        int b = pk >> 12, i = pk & 4095;
        const float* cb = cost + (size_t)b * GN * QN + i;
        float best = FLT_MAX; int bj = GN;
        for (int k = 0; k < GN; k += 64) {
            int j = k + lane;
            float v = cb[(size_t)j * QN];
            if (lexLessF(v, j, best, bj)) { best = v; bj = j; }
        }
        for (int off = 32; off > 0; off >>= 1) {
            float ov = __shfl_down(best, off, 64);
            int oj = __shfl_down(bj, off, 64);
            if (lexLessF(ov, oj, best, bj)) { best = ov; bj = oj; }
        }
        if (lane == 0) {
            u64* rm = rowmask + ((size_t)(b * QN + i)) * 4;
            rm[0] = ((bj >> 6) == 0) ? (1ull << (bj & 63)) : 0ull;
            rm[1] = ((bj >> 6) == 1) ? (1ull << (bj & 63)) : 0ull;
            rm[2] = ((bj >> 6) == 2) ? (1ull << (bj & 63)) : 0ull;
            rm[3] = ((bj >> 6) == 3) ? (1ull << (bj & 63)) : 0ull;
            atomicAdd(&colcnt[b * GN + bj], 1);
        }
    }
}

// ---------------- assign unmatched columns to cheapest unmatched row (exact f32) ----------------
__global__ __launch_bounds__(256) void k_assign(const float* __restrict__ cost,
                                                const unsigned char* __restrict__ pen,
                                                const int* __restrict__ colcnt,
                                                u64* __restrict__ rowmask,
                                                int* __restrict__ assign) {
    int b = blockIdx.x >> 8, j = blockIdx.x & 255;
    if (colcnt[b * GN + j] != 0) {
        if (threadIdx.x == 0) assign[b * GN + j] = -1;
        return;
    }
    const float* cc = cost + ((size_t)(b * GN + j)) * QN;
    const unsigned char* pp = pen + (size_t)b * QN;
    float best = FLT_MAX; int bi = INT_MAX;
    for (int k = threadIdx.x; k < QN; k += 256) {
        if (!pp[k]) {
            float v = cc[k];
            if (lexLessF(v, k, best, bi)) { best = v; bi = k; }
        }
    }
    __shared__ float sv[256];
    __shared__ int si[256];
    sv[threadIdx.x] = best; si[threadIdx.x] = bi;
    for (int s = 128; s > 0; s >>= 1) {
        __syncthreads();
        if (threadIdx.x < s) {
            float ov = sv[threadIdx.x + s]; int oi = si[threadIdx.x + s];
            if (lexLessF(ov, oi, sv[threadIdx.x], si[threadIdx.x])) {
                sv[threadIdx.x] = ov; si[threadIdx.x] = oi;
            }
        }
    }
    if (threadIdx.x == 0) {
        int r = si[0];
        assign[b * GN + j] = r;
        atomicOr(&rowmask[((size_t)(b * QN + r)) * 4 + (j >> 6)], 1ull << (j & 63));
    }
}

// ---------------- per-row outputs: selected, gt_idx ----------------
__global__ __launch_bounds__(256) void k_outrows(const u64* __restrict__ rowmask,
                                                 int* __restrict__ out) {
    int b = blockIdx.y;
    int i = blockIdx.x * 256 + threadIdx.x;
    const u64* rm = rowmask + ((size_t)(b * QN + i)) * 4;
    u64 w0 = rm[0], w1 = rm[1], w2 = rm[2], w3 = rm[3];
    int sel = (w0 | w1 | w2 | w3) ? 1 : 0;
    int g = 0;
    if (w0) g = __ffsll((long long)w0) - 1;
    else if (w1) g = 64 + __ffsll((long long)w1) - 1;
    else if (w2) g = 128 + __ffsll((long long)w2) - 1;
    else if (w3) g = 192 + __ffsll((long long)w3) - 1;
    out[(size_t)b * QN + i] = sel;
    out[(size_t)BN * QN + (size_t)b * QN + i] = g;
}

// ---------------- per-column output: matched_qidx ----------------
// Reference compares cost_f = f32(cost + 100000) for matched (penalized) rows:
// the f32 rounding at ulp(100000)=0.0078125 MERGES near-ties -> argmin breaks by
// lowest index. Replicate exactly: compare (v + 100000.0f) in f32.
__global__ __launch_bounds__(256) void k_outcols(const float* __restrict__ cost,
                                                 const u64* __restrict__ rowmask,
                                                 const int* __restrict__ assign,
                                                 int* __restrict__ out) {
    int b = blockIdx.x >> 8, j = blockIdx.x & 255;
    int* o = out + (size_t)2 * BN * QN + b * GN + j;
    int a = assign[b * GN + j];
    if (a >= 0) {
        if (threadIdx.x == 0) *o = a;
        return;
    }
    int w = j >> 6;
    u64 bit = 1ull << (j & 63);
    const float* cc = cost + ((size_t)(b * GN + j)) * QN;
    float best = FLT_MAX; int bi = INT_MAX;
    for (int k = threadIdx.x; k < QN; k += 256) {
        if (rowmask[((size_t)(b * QN + k)) * 4 + w] & bit) {
            float pv = cc[k] + 100000.0f;   // f32 merge, as in reference cost_f
            if (lexLessF(pv, k, best, bi)) { best = pv; bi = k; }
        }
    }
    __shared__ float sv[256];
    __shared__ int si[256];
    sv[threadIdx.x] = best; si[threadIdx.x] = bi;
    for (int s = 128; s > 0; s >>= 1) {
        __syncthreads();
        if (threadIdx.x < s) {
            float ov = sv[threadIdx.x + s]; int oi = si[threadIdx.x + s];
            if (lexLessF(ov, oi, sv[threadIdx.x], si[threadIdx.x])) {
                sv[threadIdx.x] = ov; si[threadIdx.x] = oi;
            }
        }
    }
    if (threadIdx.x == 0) *o = (si[0] == INT_MAX) ? 0 : si[0];
}

extern "C" void kernel_launch(void* const* d_in, const int* in_sizes, int n_in,
                              void* d_out, int out_size, void* d_ws, size_t ws_size,
                              hipStream_t stream) {
    const float* logits = (const float*)d_in[0];
    const float* pboxes = (const float*)d_in[1];
    const float* pposes = (const float*)d_in[2];
    const int* labels = (const int*)d_in[3];
    const float* gtb = (const float*)d_in[4];
    const float* gtt = (const float*)d_in[5];
    const float* gtr = (const float*)d_in[6];
    const float* img = (const float*)d_in[7];
    const float* imgt = (const float*)d_in[8];
    int* out = (int*)d_out;

    char* p = (char*)d_ws;
    float* cost = (float*)p;             p += (size_t)BN * GN * QN * 4;      // 64 MiB
    u64* rowmask = (u64*)p;              size_t rb = (size_t)BN * QN * 4 * 8; p += rb;  // 2 MiB
    int* colcnt = (int*)p;               p += (size_t)BN * GN * 4;            // 16 KiB
    int* staleCount = (int*)p;           p += 64;
    int* staleList = (int*)p;            p += (size_t)BN * QN * 4;            // 256 KiB
    unsigned char* pen = (unsigned char*)p; p += (size_t)BN * QN;             // 64 KiB
    unsigned char* fg = (unsigned char*)p;  p += (size_t)BN * QN;             // 64 KiB
    int* assign = (int*)p;               p += (size_t)BN * GN * 4;            // 16 KiB

    // zero rowmask + colcnt + staleCount (contiguous)
    int zn = (int)((rb + (size_t)BN * GN * 4 + 64) / 8);
    k_zero<<<(zn + 255) / 256, 256, 0, stream>>>(rowmask, zn);

    k_fg<<<dim3(QN / 256, BN), 256, 0, stream>>>(gtb, pboxes, fg);
    k_cost<<<BN * GN, 256, 0, stream>>>(logits, pboxes, pposes, labels, gtb, gtt, gtr,
                                        img, imgt, fg, cost, rowmask);
    k_stalepen<<<dim3(QN / 256, BN), 256, 0, stream>>>(rowmask, pen, colcnt, staleCount, staleList);
    k_stalefix<<<256, 256, 0, stream>>>(cost, rowmask, colcnt, staleCount, staleList);
    k_assign<<<BN * GN, 256, 0, stream>>>(cost, pen, colcnt, rowmask, assign);
    k_outrows<<<dim3(QN / 256, BN), 256, 0, stream>>>(rowmask, out);
    k_outcols<<<BN * GN, 256, 0, stream>>>(cost, rowmask, assign, out);
}

// Round 4
// 383.404 us; speedup vs baseline: 1.1429x; 1.1429x over previous
//
#include <hip/hip_runtime.h>
#include <cfloat>
#include <climits>
#include <math.h>

#define BN 16
#define QN 4096
#define GN 256
#define CN 80

typedef unsigned long long u64;

__device__ __forceinline__ bool lexLessF(float a, int ia, float b, int ib) {
    return (a < b) || (a == b && ia < ib);
}

// ---------------- zero init (rowmask + colcnt + staleCount) ----------------
__global__ void k_zero(u64* __restrict__ p, int n) {
    int i = blockIdx.x * blockDim.x + threadIdx.x;
    if (i < n) p[i] = 0ull;
}

// ---------------- focal class-cost table: ccls[b][c][i] ----------------
// Hoists the 3 f64 transcendentals out of the 16.78M pair loop down to
// B*Q*C = 5.24M evaluations (3.2x less), and makes k_cost's gather coalesced.
// Numerics: identical f32 op sequence to the previous in-loop version.
__global__ __launch_bounds__(256) void k_class(const float* __restrict__ logits,
                                               float* __restrict__ ccls) {
#pragma clang fp contract(off)
    const int b = blockIdx.x >> 6, iblk = blockIdx.x & 63;
    const int lane = threadIdx.x & 63, cg = threadIdx.x >> 6;  // 4 c-groups x 20
    const int i = iblk * 64 + lane;
    const float* lrow = logits + ((size_t)(b * QN + i)) * CN;
    for (int c = cg * 20; c < cg * 20 + 20; c++) {
        float x = lrow[c];
        float e = (float)exp(-(double)x);
        float pr = 1.0f / (1.0f + e);
        float om = 1.0f - pr;
        float lneg = (float)log((double)(om + 1e-8f));
        float lpos = (float)log((double)(pr + 1e-8f));
        float neg = (0.75f * (pr * pr)) * (-lneg);
        float pos = (0.25f * (om * om)) * (-lpos);
        ccls[((size_t)b * CN + c) * QN + i] = pos - neg;
    }
}

// ---------------- fg per query row (f32, exact reference order) ----------------
__global__ __launch_bounds__(256) void k_fg(const float* __restrict__ gtb,
                                            const float* __restrict__ pb,
                                            unsigned char* __restrict__ fg) {
#pragma clang fp contract(off)
    int b = blockIdx.y;
    int i = blockIdx.x * 256 + threadIdx.x;
    __shared__ float s[GN][8];
    for (int j = threadIdx.x; j < GN; j += 256) {
        const float* g = gtb + ((size_t)(b * GN + j)) * 4;
        float g0 = g[0], g1 = g[1], g2 = g[2], g3 = g[3];
        float gcx = (g0 + g2) * 0.5f, gcy = (g1 + g3) * 0.5f;
        float gw = g2 - g0, gh = g3 - g1;
        float x0 = gcx - gw * 0.5f, y0 = gcy - gh * 0.5f;
        float x1 = gcx + gw * 0.5f, y1 = gcy + gh * 0.5f;
        float w = x1 - x0, h = y1 - y0;
        s[j][0] = x0; s[j][1] = y0; s[j][2] = x1; s[j][3] = y1;
        s[j][4] = gcx - 2.5f * w; s[j][5] = gcx + 2.5f * w;
        s[j][6] = gcy - 2.5f * h; s[j][7] = gcy + 2.5f * h;
    }
    __syncthreads();
    const float4 bb = *reinterpret_cast<const float4*>(pb + ((size_t)(b * QN + i)) * 4);
    float ax = (bb.x + bb.z) * 0.5f, ay = (bb.y + bb.w) * 0.5f;
    bool anyib = false, anyic = false;
    for (int j = 0; j < GN; j++) {
        bool ib = (ax > s[j][0]) && (ax < s[j][2]) && (ay > s[j][1]) && (ay < s[j][3]);
        bool ic = (ax > s[j][4]) && (ax < s[j][5]) && (ay > s[j][6]) && (ay < s[j][7]);
        anyib |= ib; anyic |= ic;
    }
    fg[(size_t)b * QN + i] = (anyib || anyic) ? 1 : 0;
}

// ---------------- cost matrix (f32) + per-column dk selection ----------------
__global__ __launch_bounds__(256) void k_cost(
    const float* __restrict__ ccls, const float* __restrict__ pboxes,
    const float* __restrict__ pposes, const int* __restrict__ labels,
    const float* __restrict__ gtb, const float* __restrict__ gtt,
    const float* __restrict__ gtr, const float* __restrict__ img,
    const float* __restrict__ imgt, const unsigned char* __restrict__ fg,
    float* __restrict__ cost, u64* __restrict__ rowmask) {
#pragma clang fp contract(off)
    const int t = threadIdx.x;
    const int b = blockIdx.x >> 8, j = blockIdx.x & 255;
    const int lab = labels[b * GN + j];
    const float* g = gtb + ((size_t)(b * GN + j)) * 4;
    const float g0 = g[0], g1 = g[1], g2 = g[2], g3 = g[3];
    const float* it = imgt + ((size_t)(b * GN + j)) * 4;
    const float gn0 = g0 / it[0], gn1 = g1 / it[1], gn2 = g2 / it[2], gn3 = g3 / it[3];
    const float im0 = img[b * 4 + 0], im1 = img[b * 4 + 1], im2 = img[b * 4 + 2], im3 = img[b * 4 + 3];
    const float ga = (g2 - g0) * (g3 - g1);
    const float gcx = (g0 + g2) * 0.5f, gcy = (g1 + g3) * 0.5f;
    const float gw = g2 - g0, gh = g3 - g1;
    const float X0 = gcx - gw * 0.5f, Y0 = gcy - gh * 0.5f;
    const float X1 = gcx + gw * 0.5f, Y1 = gcy + gh * 0.5f;
    const float W = X1 - X0, H = Y1 - Y0;
    const float LOX = gcx - 2.5f * W, HIX = gcx + 2.5f * W;
    const float LOY = gcy - 2.5f * H, HIY = gcy + 2.5f * H;
    const float t0 = gtt[(b * GN + j) * 3 + 0], t1 = gtt[(b * GN + j) * 3 + 1], t2 = gtt[(b * GN + j) * 3 + 2];
    const float r0 = gtr[(b * GN + j) * 3 + 0], r1 = gtr[(b * GN + j) * 3 + 1], r2 = gtr[(b * GN + j) * 3 + 2];

    float cv[5]; int ci[5]; float iv[5];
#pragma unroll
    for (int k = 0; k < 5; k++) { cv[k] = FLT_MAX; ci[k] = INT_MAX; iv[k] = -1.0f; }

    float* crow = cost + ((size_t)(b * GN + j)) * QN;
    const float* crcls = ccls + ((size_t)b * CN + lab) * QN;   // coalesced in i

    for (int kk = 0; kk < QN / 256; kk++) {
        int i = t + kk * 256;
        const float4 bx = *reinterpret_cast<const float4*>(pboxes + ((size_t)(b * QN + i)) * 4);
        const float b0 = bx.x, b1 = bx.y, b2 = bx.z, b3 = bx.w;
        const float* ps = pposes + ((size_t)(b * QN + i)) * 6;
        const float p0 = ps[0], p1 = ps[1], p2 = ps[2], p3 = ps[3], p4 = ps[4], p5 = ps[5];
        const float cc = crcls[i];
        const unsigned char fgv = fg[(size_t)b * QN + i];

        // iou / giou (f32, reference op order)
        float a1 = (b2 - b0) * (b3 - b1);
        float ltx = fmaxf(b0, g0), lty = fmaxf(b1, g1);
        float rbx = fminf(b2, g2), rby = fminf(b3, g3);
        float w = fmaxf(rbx - ltx, 0.0f), h = fmaxf(rby - lty, 0.0f);
        float inter = w * h;
        float uni = (a1 + ga) - inter;
        float iou = inter / uni;
        float eltx = fminf(b0, g0), elty = fminf(b1, g1);
        float erbx = fmaxf(b2, g2), erby = fmaxf(b3, g3);
        float ew = fmaxf(erbx - eltx, 0.0f), eh = fmaxf(erby - elty, 0.0f);
        float earea = ew * eh;
        float giou = iou - (earea - uni) / earea;

        // normalized bbox L1 (sequential f32)
        float cb = fabsf(b0 / im0 - gn0);
        cb = cb + fabsf(b1 / im1 - gn1);
        cb = cb + fabsf(b2 / im2 - gn2);
        cb = cb + fabsf(b3 / im3 - gn3);
        // pose L1
        float ct = fabsf(p0 - t0); ct = ct + fabsf(p1 - t1); ct = ct + fabsf(p2 - t2);
        float cr = fabsf(p3 - r0); cr = cr + fabsf(p4 - r1); cr = cr + fabsf(p5 - r2);
        // both = in_box & in_ctr
        float ax = (b0 + b2) * 0.5f, ay = (b1 + b3) * 0.5f;
        bool ib = (ax > X0) && (ax < X1) && (ay > Y0) && (ay < Y1);
        bool ic = (ax > LOX) && (ax < HIX) && (ay > LOY) && (ay < HIY);
        bool nb = !(ib && ic);

        // combine fully in f32, reference left-to-right order
        float d = 5.0f * cb;
        d = d + 2.0f * cc;
        d = d + 2.0f * (-giou);
        d = d + (nb ? 100.0f : 0.0f);
        d = d + ct;
        d = d + cr;
        d = d + (fgv ? 0.0f : 10000.0f);

        crow[i] = d;

        // per-thread bottom-5 (cost,i) lex, ascending
        if (lexLessF(d, i, cv[4], ci[4])) {
            int k = 4;
            while (k > 0 && lexLessF(d, i, cv[k - 1], ci[k - 1])) {
                cv[k] = cv[k - 1]; ci[k] = ci[k - 1]; k--;
            }
            cv[k] = d; ci[k] = i;
        }
        // per-thread top-5 iou, descending
        if (iou > iv[4]) {
            int k = 4;
            while (k > 0 && iou > iv[k - 1]) { iv[k] = iv[k - 1]; k--; }
            iv[k] = iou;
        }
    }

    __shared__ float scv[256 * 5];
    __shared__ int sci[256 * 5];
    __shared__ float siv[256 * 5];
#pragma unroll
    for (int k = 0; k < 5; k++) { scv[t * 5 + k] = cv[k]; sci[t * 5 + k] = ci[k]; siv[t * 5 + k] = iv[k]; }

    for (int s = 128; s > 0; s >>= 1) {
        __syncthreads();
        if (t < s) {
            float av[5], bv[5], rv[5];
            int ai[5], bi[5], ri[5];
#pragma unroll
            for (int k = 0; k < 5; k++) {
                av[k] = scv[t * 5 + k]; ai[k] = sci[t * 5 + k];
                bv[k] = scv[(t + s) * 5 + k]; bi[k] = sci[(t + s) * 5 + k];
            }
            int pa = 0, pb = 0;
#pragma unroll
            for (int k = 0; k < 5; k++) {
                bool takeA = lexLessF(av[pa], ai[pa], bv[pb], bi[pb]);
                if (takeA) { rv[k] = av[pa]; ri[k] = ai[pa]; pa++; }
                else { rv[k] = bv[pb]; ri[k] = bi[pb]; pb++; }
            }
#pragma unroll
            for (int k = 0; k < 5; k++) { scv[t * 5 + k] = rv[k]; sci[t * 5 + k] = ri[k]; }
            float fa[5], fb[5], fr[5];
#pragma unroll
            for (int k = 0; k < 5; k++) { fa[k] = siv[t * 5 + k]; fb[k] = siv[(t + s) * 5 + k]; }
            pa = 0; pb = 0;
#pragma unroll
            for (int k = 0; k < 5; k++) {
                if (fa[pa] >= fb[pb]) { fr[k] = fa[pa]; pa++; }
                else { fr[k] = fb[pb]; pb++; }
            }
#pragma unroll
            for (int k = 0; k < 5; k++) siv[t * 5 + k] = fr[k];
        }
    }

    if (t == 0) {
#pragma clang fp contract(off)
        float sum = ((((siv[0] + siv[1]) + siv[2]) + siv[3]) + siv[4]);  // sequential, desc order
        int dk = (int)sum;          // trunc toward zero (sum >= 0)
        if (dk < 1) dk = 1;
        if (dk > 5) dk = 5;
        for (int k = 0; k < dk; k++) {
            int i = sci[k];
            atomicOr(&rowmask[((size_t)(b * QN + i)) * 4 + (j >> 6)], 1ull << (j & 63));
        }
    }
}

// ---------------- stale detect + pen + colcnt (non-stale rows) ----------------
__global__ __launch_bounds__(256) void k_stalepen(u64* __restrict__ rowmask,
                                                  unsigned char* __restrict__ pen,
                                                  int* __restrict__ colcnt,
                                                  int* __restrict__ staleCount,
                                                  int* __restrict__ staleList) {
    int b = blockIdx.y;
    int i = blockIdx.x * 256 + threadIdx.x;
    u64* rm = rowmask + ((size_t)(b * QN + i)) * 4;
    u64 w0 = rm[0], w1 = rm[1], w2 = rm[2], w3 = rm[3];
    int cnt = __popcll(w0) + __popcll(w1) + __popcll(w2) + __popcll(w3);
    pen[(size_t)b * QN + i] = (cnt > 0) ? 1 : 0;
    if (cnt > 1) {
        int idx = atomicAdd(staleCount, 1);
        staleList[idx] = (b << 12) | i;
    } else if (cnt == 1) {
        u64 w; int base;
        if (w0) { w = w0; base = 0; }
        else if (w1) { w = w1; base = 64; }
        else if (w2) { w = w2; base = 128; }
        else { w = w3; base = 192; }
        int j = base + (__ffsll((long long)w) - 1);
        atomicAdd(&colcnt[b * GN + j], 1);
    }
}

// ---------------- stale fix: row -> one_hot(argmin_j cost) (unpenalized, exact f32) ----------------
__global__ __launch_bounds__(256) void k_stalefix(const float* __restrict__ cost,
                                                  u64* __restrict__ rowmask,
                                                  int* __restrict__ colcnt,
                                                  const int* __restrict__ staleCount,
                                                  const int* __restrict__ staleList) {
    int gtid = blockIdx.x * blockDim.x + threadIdx.x;
    int wid = gtid >> 6;
    int lane = threadIdx.x & 63;
    int nw = (gridDim.x * blockDim.x) >> 6;
    int n = *staleCount;
    for (int e = wid; e < n; e += nw) {
        int pk = staleList[e];
        int b = pk >> 12, i = pk & 4095;
        const float* cb = cost + (size_t)b * GN * QN + i;
        float best = FLT_MAX; int bj = GN;
        for (int k = 0; k < GN; k += 64) {
            int j = k + lane;
            float v = cb[(size_t)j * QN];
            if (lexLessF(v, j, best, bj)) { best = v; bj = j; }
        }
        for (int off = 32; off > 0; off >>= 1) {
            float ov = __shfl_down(best, off, 64);
            int oj = __shfl_down(bj, off, 64);
            if (lexLessF(ov, oj, best, bj)) { best = ov; bj = oj; }
        }
        if (lane == 0) {
            u64* rm = rowmask + ((size_t)(b * QN + i)) * 4;
            rm[0] = ((bj >> 6) == 0) ? (1ull << (bj & 63)) : 0ull;
            rm[1] = ((bj >> 6) == 1) ? (1ull << (bj & 63)) : 0ull;
            rm[2] = ((bj >> 6) == 2) ? (1ull << (bj & 63)) : 0ull;
            rm[3] = ((bj >> 6) == 3) ? (1ull << (bj & 63)) : 0ull;
            atomicAdd(&colcnt[b * GN + bj], 1);
        }
    }
}

// ---------------- assign unmatched columns to cheapest unmatched row (exact f32) ----------------
__global__ __launch_bounds__(256) void k_assign(const float* __restrict__ cost,
                                                const unsigned char* __restrict__ pen,
                                                const int* __restrict__ colcnt,
                                                u64* __restrict__ rowmask,
                                                int* __restrict__ assign) {
    int b = blockIdx.x >> 8, j = blockIdx.x & 255;
    if (colcnt[b * GN + j] != 0) {
        if (threadIdx.x == 0) assign[b * GN + j] = -1;
        return;
    }
    const float* cc = cost + ((size_t)(b * GN + j)) * QN;
    const unsigned char* pp = pen + (size_t)b * QN;
    float best = FLT_MAX; int bi = INT_MAX;
    for (int k = threadIdx.x; k < QN; k += 256) {
        if (!pp[k]) {
            float v = cc[k];
            if (lexLessF(v, k, best, bi)) { best = v; bi = k; }
        }
    }
    __shared__ float sv[256];
    __shared__ int si[256];
    sv[threadIdx.x] = best; si[threadIdx.x] = bi;
    for (int s = 128; s > 0; s >>= 1) {
        __syncthreads();
        if (threadIdx.x < s) {
            float ov = sv[threadIdx.x + s]; int oi = si[threadIdx.x + s];
            if (lexLessF(ov, oi, sv[threadIdx.x], si[threadIdx.x])) {
                sv[threadIdx.x] = ov; si[threadIdx.x] = oi;
            }
        }
    }
    if (threadIdx.x == 0) {
        int r = si[0];
        assign[b * GN + j] = r;
        atomicOr(&rowmask[((size_t)(b * QN + r)) * 4 + (j >> 6)], 1ull << (j & 63));
    }
}

// ---------------- per-row outputs: selected, gt_idx ----------------
__global__ __launch_bounds__(256) void k_outrows(const u64* __restrict__ rowmask,
                                                 int* __restrict__ out) {
    int b = blockIdx.y;
    int i = blockIdx.x * 256 + threadIdx.x;
    const u64* rm = rowmask + ((size_t)(b * QN + i)) * 4;
    u64 w0 = rm[0], w1 = rm[1], w2 = rm[2], w3 = rm[3];
    int sel = (w0 | w1 | w2 | w3) ? 1 : 0;
    int g = 0;
    if (w0) g = __ffsll((long long)w0) - 1;
    else if (w1) g = 64 + __ffsll((long long)w1) - 1;
    else if (w2) g = 128 + __ffsll((long long)w2) - 1;
    else if (w3) g = 192 + __ffsll((long long)w3) - 1;
    out[(size_t)b * QN + i] = sel;
    out[(size_t)BN * QN + (size_t)b * QN + i] = g;
}

// ---------------- per-column output: matched_qidx ----------------
// Reference compares cost_f = f32(cost + 100000) for matched (penalized) rows:
// the f32 rounding at ulp(100000)=0.0078125 MERGES near-ties -> argmin breaks by
// lowest index. Replicate exactly: compare (v + 100000.0f) in f32.
__global__ __launch_bounds__(256) void k_outcols(const float* __restrict__ cost,
                                                 const u64* __restrict__ rowmask,
                                                 const int* __restrict__ assign,
                                                 int* __restrict__ out) {
    int b = blockIdx.x >> 8, j = blockIdx.x & 255;
    int* o = out + (size_t)2 * BN * QN + b * GN + j;
    int a = assign[b * GN + j];
    if (a >= 0) {
        if (threadIdx.x == 0) *o = a;
        return;
    }
    int w = j >> 6;
    u64 bit = 1ull << (j & 63);
    const float* cc = cost + ((size_t)(b * GN + j)) * QN;
    float best = FLT_MAX; int bi = INT_MAX;
    for (int k = threadIdx.x; k < QN; k += 256) {
        if (rowmask[((size_t)(b * QN + k)) * 4 + w] & bit) {
            float pv = cc[k] + 100000.0f;   // f32 merge, as in reference cost_f
            if (lexLessF(pv, k, best, bi)) { best = pv; bi = k; }
        }
    }
    __shared__ float sv[256];
    __shared__ int si[256];
    sv[threadIdx.x] = best; si[threadIdx.x] = bi;
    for (int s = 128; s > 0; s >>= 1) {
        __syncthreads();
        if (threadIdx.x < s) {
            float ov = sv[threadIdx.x + s]; int oi = si[threadIdx.x + s];
            if (lexLessF(ov, oi, sv[threadIdx.x], si[threadIdx.x])) {
                sv[threadIdx.x] = ov; si[threadIdx.x] = oi;
            }
        }
    }
    if (threadIdx.x == 0) *o = (si[0] == INT_MAX) ? 0 : si[0];
}

extern "C" void kernel_launch(void* const* d_in, const int* in_sizes, int n_in,
                              void* d_out, int out_size, void* d_ws, size_t ws_size,
                              hipStream_t stream) {
    const float* logits = (const float*)d_in[0];
    const float* pboxes = (const float*)d_in[1];
    const float* pposes = (const float*)d_in[2];
    const int* labels = (const int*)d_in[3];
    const float* gtb = (const float*)d_in[4];
    const float* gtt = (const float*)d_in[5];
    const float* gtr = (const float*)d_in[6];
    const float* img = (const float*)d_in[7];
    const float* imgt = (const float*)d_in[8];
    int* out = (int*)d_out;

    char* p = (char*)d_ws;
    float* cost = (float*)p;             p += (size_t)BN * GN * QN * 4;      // 64 MiB
    float* ccls = (float*)p;             p += (size_t)BN * CN * QN * 4;      // 20 MiB
    u64* rowmask = (u64*)p;              size_t rb = (size_t)BN * QN * 4 * 8; p += rb;  // 2 MiB
    int* colcnt = (int*)p;               p += (size_t)BN * GN * 4;            // 16 KiB
    int* staleCount = (int*)p;           p += 64;
    int* staleList = (int*)p;            p += (size_t)BN * QN * 4;            // 256 KiB
    unsigned char* pen = (unsigned char*)p; p += (size_t)BN * QN;             // 64 KiB
    unsigned char* fg = (unsigned char*)p;  p += (size_t)BN * QN;             // 64 KiB
    int* assign = (int*)p;               p += (size_t)BN * GN * 4;            // 16 KiB

    // zero rowmask + colcnt + staleCount (contiguous)
    int zn = (int)((rb + (size_t)BN * GN * 4 + 64) / 8);
    k_zero<<<(zn + 255) / 256, 256, 0, stream>>>(rowmask, zn);

    k_class<<<BN * 64, 256, 0, stream>>>(logits, ccls);
    k_fg<<<dim3(QN / 256, BN), 256, 0, stream>>>(gtb, pboxes, fg);
    k_cost<<<BN * GN, 256, 0, stream>>>(ccls, pboxes, pposes, labels, gtb, gtt, gtr,
                                        img, imgt, fg, cost, rowmask);
    k_stalepen<<<dim3(QN / 256, BN), 256, 0, stream>>>(rowmask, pen, colcnt, staleCount, staleList);
    k_stalefix<<<256, 256, 0, stream>>>(cost, rowmask, colcnt, staleCount, staleList);
    k_assign<<<BN * GN, 256, 0, stream>>>(cost, pen, colcnt, rowmask, assign);
    k_outrows<<<dim3(QN / 256, BN), 256, 0, stream>>>(rowmask, out);
    k_outcols<<<BN * GN, 256, 0, stream>>>(cost, rowmask, assign, out);
}